// Round 4
// baseline (205.867 us; speedup 1.0000x reference)
//
#include <hip/hip_runtime.h>
#include <cstddef>
#include <cstdint>

typedef __attribute__((ext_vector_type(8))) short bf16x8;
typedef __attribute__((ext_vector_type(4))) float f32x4;

static __device__ __forceinline__ short f2bf(float f) {
    union { float f; unsigned u; } x;
    x.f = f;
    unsigned r = (x.u + 0x7FFFu + ((x.u >> 16) & 1u)) >> 16;  // RNE
    return (short)r;
}
// 2-op bf16 conversion (round-half-away). Fine for positive softmax weights.
static __device__ __forceinline__ short f2bf_fast(float f) {
    union { float f; unsigned u; } x;
    x.f = f;
    return (short)((x.u + 0x8000u) >> 16);
}

typedef __attribute__((address_space(3))) unsigned lds_u;
typedef const __attribute__((address_space(1))) unsigned glb_u;
static __device__ __forceinline__ void gld_lds16(const void* g, void* l) {
    __builtin_amdgcn_global_load_lds((glb_u*)g, (lds_u*)l, 16, 0, 0);
}

// ---------------------------------------------------------------------------
// prep: blocks [0,7168) convert x,ctx fp32->bf16; [7168,8448) transpose+convert
// weights to BT layout (Wk|Wv fused into wkvT [1024,768]).
// ---------------------------------------------------------------------------
__global__ __launch_bounds__(256) void prep_kernel(
    const float* __restrict__ x, const float* __restrict__ c,
    const float* __restrict__ Wq, const float* __restrict__ Wk,
    const float* __restrict__ Wv, const float* __restrict__ Wo,
    short* __restrict__ xb, short* __restrict__ cb,
    short* __restrict__ wqT, short* __restrict__ wkvT, short* __restrict__ woT)
{
    const int bid = blockIdx.x;
    const int tid = threadIdx.x;
    if (bid < 7168) {
        int i = bid * 256 + tid;                 // float4 index
        int nn1 = (8192 * 512) >> 2;
        const float* src; short* dst; int off;
        if (i < nn1) { src = x; dst = xb; off = i; }
        else { src = c; dst = cb; off = i - nn1; }
        float4 v = ((const float4*)src)[off];
        ushort4 w;
        w.x = (unsigned short)f2bf(v.x); w.y = (unsigned short)f2bf(v.y);
        w.z = (unsigned short)f2bf(v.z); w.w = (unsigned short)f2bf(v.w);
        ((ushort4*)dst)[off] = w;
        return;
    }
    // weight transpose part
    __shared__ float T[32][33];
    int w = bid - 7168;
    const float* src; short* dst; int R, t;
    if (w < 256)       { src = Wq; dst = wqT;  R = 512; t = w; }
    else if (w < 640)  { src = Wk; dst = wkvT; R = 768; t = w - 256; }
    else if (w < 1024) { src = Wv; dst = wkvT + (size_t)512 * 768; R = 768; t = w - 640; }
    else               { src = Wo; dst = woT;  R = 512; t = w - 1024; }
    const int xt = t & 15, yt = t >> 4;
    {
        int r = tid >> 3, c4 = (tid & 7) * 4;
        float4 v = *(const float4*)&src[(size_t)(yt * 32 + r) * 512 + xt * 32 + c4];
        T[r][c4] = v.x; T[r][c4 + 1] = v.y; T[r][c4 + 2] = v.z; T[r][c4 + 3] = v.w;
    }
    __syncthreads();
    {
        int cc = tid >> 3, r4 = (tid & 7) * 4;
        ushort4 o;
        o.x = (unsigned short)f2bf(T[r4][cc]);     o.y = (unsigned short)f2bf(T[r4 + 1][cc]);
        o.z = (unsigned short)f2bf(T[r4 + 2][cc]); o.w = (unsigned short)f2bf(T[r4 + 3][cc]);
        *(ushort4*)&dst[(size_t)(xt * 32 + cc) * R + yt * 32 + r4] = o;
    }
}

// ---------------------------------------------------------------------------
// V transpose (bf16): kvb v-half [4][1024][512] (ld 1024) -> vT [4][512][1024]
// ---------------------------------------------------------------------------
__global__ __launch_bounds__(256) void vtrans_kernel(
    const short* __restrict__ v, short* __restrict__ vT)
{
    __shared__ short T[32][33];
    const int b = blockIdx.z, yt = blockIdx.y, xt = blockIdx.x;
    const int tid = threadIdx.x;
    {
        int r = tid >> 3, c4 = (tid & 7) * 4;
        ushort4 vv = *(const ushort4*)&v[((size_t)(b * 1024 + yt * 32 + r)) * 1024 + xt * 32 + c4];
        T[r][c4] = (short)vv.x; T[r][c4 + 1] = (short)vv.y;
        T[r][c4 + 2] = (short)vv.z; T[r][c4 + 3] = (short)vv.w;
    }
    __syncthreads();
    {
        int cc = tid >> 3, r4 = (tid & 7) * 4;
        ushort4 w;
        w.x = (unsigned short)T[r4][cc];     w.y = (unsigned short)T[r4 + 1][cc];
        w.z = (unsigned short)T[r4 + 2][cc]; w.w = (unsigned short)T[r4 + 3][cc];
        *(ushort4*)&vT[((size_t)(b * 512 + xt * 32 + cc)) * 1024 + yt * 32 + r4] = w;
    }
}

// ---------------------------------------------------------------------------
// GEMM core: BM=64, BN=128, BK=64, 4 waves (2x2, wave tile 32x64), dbuf LDS,
// one barrier/iter. Chunk-major LDS; 16 MFMA + 12 ds_read_b128 + 6 DMA / iter.
// ---------------------------------------------------------------------------
static __device__ __forceinline__ void gemm_core64(
    const short* __restrict__ A, const short* __restrict__ BT, int K,
    int bm, int bn, short* As, short* Bs, f32x4 acc[2][4])
{
    const int tid  = threadIdx.x;
    const int lane = tid & 63;
    const int wave = tid >> 6;
    const int lm   = lane & 15;
    const int quad = lane >> 4;
    const int wm = (wave >> 1) * 32;
    const int wn = (wave & 1) * 64;
    const int ca = tid >> 6, ra = tid & 63;     // A: 2 chunks/thread
    const int cb = tid >> 7, rb = tid & 127;    // B: 4 chunks/thread

    {   // prologue: buf 0
        const short* Ag = &A[(size_t)(bm + ra) * K];
        gld_lds16(Ag + ca * 8,       &As[(ca * 64 + ra) * 8]);
        gld_lds16(Ag + (ca + 4) * 8, &As[((ca + 4) * 64 + ra) * 8]);
        const short* Bg = &BT[(size_t)(bn + rb) * K];
        #pragma unroll
        for (int p = 0; p < 4; ++p)
            gld_lds16(Bg + (cb + 2 * p) * 8, &Bs[((cb + 2 * p) * 128 + rb) * 8]);
    }

    const int nit = K >> 6;
    for (int it = 0; it < nit; ++it) {
        short* Ac = As + (it & 1) * 4096;
        short* Bc = Bs + (it & 1) * 8192;
        __syncthreads();                         // cur buf ready; prev reads done
        if (it + 1 < nit) {
            short* An = As + ((it + 1) & 1) * 4096;
            short* Bn = Bs + ((it + 1) & 1) * 8192;
            const short* Ag = &A[(size_t)(bm + ra) * K + (it + 1) * 64];
            gld_lds16(Ag + ca * 8,       &An[(ca * 64 + ra) * 8]);
            gld_lds16(Ag + (ca + 4) * 8, &An[((ca + 4) * 64 + ra) * 8]);
            const short* Bg = &BT[(size_t)(bn + rb) * K + (it + 1) * 64];
            #pragma unroll
            for (int p = 0; p < 4; ++p)
                gld_lds16(Bg + (cb + 2 * p) * 8, &Bn[((cb + 2 * p) * 128 + rb) * 8]);
        }
        #pragma unroll
        for (int h = 0; h < 2; ++h) {
            bf16x8 af[2], bfr[4];
            #pragma unroll
            for (int i = 0; i < 2; ++i)
                af[i] = *(const bf16x8*)&Ac[((h * 4 + quad) * 64 + wm + i * 16 + lm) * 8];
            #pragma unroll
            for (int j = 0; j < 4; ++j)
                bfr[j] = *(const bf16x8*)&Bc[((h * 4 + quad) * 128 + wn + j * 16 + lm) * 8];
            #pragma unroll
            for (int i = 0; i < 2; ++i)
                #pragma unroll
                for (int j = 0; j < 4; ++j)
                    acc[i][j] = __builtin_amdgcn_mfma_f32_16x16x32_bf16(
                        af[i], bfr[j], acc[i][j], 0, 0, 0);
        }
    }
}

// Fused Q + KV projection. blocks [0,512): q = xb@wqT; [512,1024): kv = cb@wkvT.
__global__ __launch_bounds__(256, 3) void qkv_kernel(
    const short* __restrict__ xb, const short* __restrict__ cb,
    const short* __restrict__ wqT, const short* __restrict__ wkvT,
    short* __restrict__ qb, short* __restrict__ kvb)
{
    __shared__ short As[2 * 4096];
    __shared__ short Bs[2 * 8192];
    const int bid = blockIdx.x;
    const short *A, *BT; short* C; int K, ldc, bm, bn;
    if (bid < 512) { A = xb; BT = wqT;  C = qb;  K = 512; ldc = 512;
                     bm = (bid >> 2) * 64; bn = (bid & 3) * 128; }
    else { int b2 = bid - 512; A = cb; BT = wkvT; C = kvb; K = 768; ldc = 1024;
           bm = (b2 >> 3) * 64; bn = (b2 & 7) * 128; }

    f32x4 acc[2][4] = {};
    gemm_core64(A, BT, K, bm, bn, As, Bs, acc);

    const int lane = threadIdx.x & 63, wave = threadIdx.x >> 6;
    const int lm = lane & 15, quad = lane >> 4;
    const int wm = (wave >> 1) * 32, wn = (wave & 1) * 64;
    #pragma unroll
    for (int j = 0; j < 4; ++j) {
        int col = bn + wn + j * 16 + lm;
        #pragma unroll
        for (int i = 0; i < 2; ++i) {
            int row0 = bm + wm + i * 16 + quad * 4;
            #pragma unroll
            for (int r = 0; r < 4; ++r)
                C[(size_t)(row0 + r) * ldc + col] = f2bf(acc[i][j][r]);
        }
    }
}

// Output projection: out = ob@woT + bo (fp32). Grid 512.
__global__ __launch_bounds__(256, 3) void ogemm_kernel(
    const short* __restrict__ ob, const short* __restrict__ woT,
    const float* __restrict__ bias, float* __restrict__ out)
{
    __shared__ short As[2 * 4096];
    __shared__ short Bs[2 * 8192];
    const int bid = blockIdx.x;
    const int bm = (bid >> 2) * 64, bn = (bid & 3) * 128;

    f32x4 acc[2][4] = {};
    gemm_core64(ob, woT, 512, bm, bn, As, Bs, acc);

    const int lane = threadIdx.x & 63, wave = threadIdx.x >> 6;
    const int lm = lane & 15, quad = lane >> 4;
    const int wm = (wave >> 1) * 32, wn = (wave & 1) * 64;
    #pragma unroll
    for (int j = 0; j < 4; ++j) {
        int col = bn + wn + j * 16 + lm;
        float bv = bias[col];
        #pragma unroll
        for (int i = 0; i < 2; ++i) {
            int row0 = bm + wm + i * 16 + quad * 4;
            #pragma unroll
            for (int r = 0; r < 4; ++r)
                out[(size_t)(row0 + r) * 512 + col] = acc[i][j][r] + bv;
        }
    }
}

// ---------------------------------------------------------------------------
// Flash attention, fixed-max softmax. Block = (b,h,128 q-rows), 4 waves.
// Two 64-row q-subtiles (u=0,1) per wave interleave: u1's QK MFMAs overlap
// u0's softmax VALU. K/V dbuf (one barrier/tile). P round-trips through the
// dead Q-staging LDS per (u,wave) with XOR-swizzled chunks (reads free).
// ---------------------------------------------------------------------------
__global__ __launch_bounds__(256, 3) void attn_kernel(
    const short* __restrict__ q, const short* __restrict__ k,
    const short* __restrict__ vT, short* __restrict__ o)
{
    __shared__ short Qs[8192];          // Q staging (2x64x64), then P buffers
    __shared__ short Ks[2 * 4096];
    __shared__ short Vs[2 * 4096];

    const int tid  = threadIdx.x;
    const int lane = tid & 63;
    const int wave = tid >> 6;
    const int lm   = lane & 15;
    const int quad = lane >> 4;
    const int qt = blockIdx.x, h = blockIdx.y, b = blockIdx.z;
    const size_t qrow0 = (size_t)b * 2048 + qt * 128;
    const size_t krow0 = (size_t)b * 1024;
    const int hcol = h * 64;
    const size_t vrow0 = ((size_t)b * 8 + h) * 64;

    // prologue: stage Q (1024 chunks) + K/V tile 0
    #pragma unroll
    for (int p = 0; p < 4; ++p) {
        int idx = p * 256 + tid;
        int u = idx >> 9, c = (idx >> 6) & 7, r = idx & 63;
        gld_lds16(&q[(qrow0 + u * 64 + r) * 512 + hcol + c * 8], &Qs[idx * 8]);
    }
    #pragma unroll
    for (int p = 0; p < 2; ++p) {
        int idx = p * 256 + tid;
        int c = idx >> 6, r = idx & 63;
        gld_lds16(&k[(krow0 + r) * 1024 + hcol + c * 8], &Ks[idx * 8]);
        gld_lds16(&vT[(vrow0 + r) * 1024 + c * 8], &Vs[idx * 8]);
    }
    __syncthreads();
    bf16x8 qf[2][2];
    #pragma unroll
    for (int u = 0; u < 2; ++u)
        #pragma unroll
        for (int hf = 0; hf < 2; ++hf)
            qf[u][hf] = *(const bf16x8*)&Qs[u * 4096 +
                         ((hf * 4 + quad) * 64 + wave * 16 + lm) * 8];
    // NOTE: Qs is reused as P buffer; first P write happens after the t-loop's
    // first __syncthreads, which orders it after all waves' qf reads.

    // hoisted P-buffer addressing (wave-private region per (u,wave))
    const int pb0 = (0 * 4 + wave) * 1024;
    const int pb1 = (1 * 4 + wave) * 1024;
    int rowo[4], swz[4];
    #pragma unroll
    for (int r = 0; r < 4; ++r) {
        int row = quad * 4 + r;
        rowo[r] = row * 64 + (lm & 7);
        swz[r]  = row & 7;
    }
    int pr[2][2];
    #pragma unroll
    for (int u = 0; u < 2; ++u)
        #pragma unroll
        for (int hf = 0; hf < 2; ++hf)
            pr[u][hf] = (u * 4 + wave) * 1024 + lm * 64 +
                        (((hf * 4 + quad) ^ (lm & 7)) << 3);

    constexpr float C1 = 0.18033688f;   // 0.125 * log2(e)
    constexpr float C2 = 11.5415603f;   // 8 * log2(e)

    f32x4 oacc[2][4] = {};
    float lrow[2][4] = {};

    for (int t = 0; t < 16; ++t) {
        const short* Kc = &Ks[(t & 1) * 4096];
        const short* Vc = &Vs[(t & 1) * 4096];
        __syncthreads();
        if (t + 1 < 16) {
            short* Kn = &Ks[((t + 1) & 1) * 4096];
            short* Vn = &Vs[((t + 1) & 1) * 4096];
            #pragma unroll
            for (int p = 0; p < 2; ++p) {
                int idx = p * 256 + tid;
                int c = idx >> 6, r = idx & 63;
                gld_lds16(&k[(krow0 + (t + 1) * 64 + r) * 1024 + hcol + c * 8], &Kn[idx * 8]);
                gld_lds16(&vT[(vrow0 + r) * 1024 + (t + 1) * 64 + c * 8], &Vn[idx * 8]);
            }
        }

        // K fragments once for both q-subtiles
        bf16x8 kf[4][2];
        #pragma unroll
        for (int j = 0; j < 4; ++j)
            #pragma unroll
            for (int hf = 0; hf < 2; ++hf)
                kf[j][hf] = *(const bf16x8*)&Kc[((hf * 4 + quad) * 64 + j * 16 + lm) * 8];

        // per subtile: S = Q K^T, then softmax + P write
        #pragma unroll
        for (int u = 0; u < 2; ++u) {
            f32x4 sacc[4] = {};
            #pragma unroll
            for (int j = 0; j < 4; ++j) {
                sacc[j] = __builtin_amdgcn_mfma_f32_16x16x32_bf16(qf[u][0], kf[j][0], sacc[j], 0, 0, 0);
                sacc[j] = __builtin_amdgcn_mfma_f32_16x16x32_bf16(qf[u][1], kf[j][1], sacc[j], 0, 0, 0);
            }
            const int pb = u ? pb1 : pb0;
            #pragma unroll
            for (int r = 0; r < 4; ++r) {
                float lsum = 0.0f;
                #pragma unroll
                for (int j = 0; j < 4; ++j) {
                    float pv = exp2f(fmaf(sacc[j][r], C1, -C2));
                    lsum += pv;
                    int cc = (2 * j + (lm >> 3)) ^ swz[r];
                    Qs[pb + rowo[r] + (cc << 3)] = f2bf_fast(pv);
                }
                lrow[u][r] += lsum;
            }
        }

        // V fragments once, P fragments, O += P @ V
        bf16x8 vf[4][2];
        #pragma unroll
        for (int j = 0; j < 4; ++j)
            #pragma unroll
            for (int hf = 0; hf < 2; ++hf)
                vf[j][hf] = *(const bf16x8*)&Vc[((hf * 4 + quad) * 64 + j * 16 + lm) * 8];
        #pragma unroll
        for (int u = 0; u < 2; ++u) {
            bf16x8 pf0 = *(const bf16x8*)&Qs[pr[u][0]];
            bf16x8 pf1 = *(const bf16x8*)&Qs[pr[u][1]];
            #pragma unroll
            for (int j = 0; j < 4; ++j) {
                oacc[u][j] = __builtin_amdgcn_mfma_f32_16x16x32_bf16(pf0, vf[j][0], oacc[u][j], 0, 0, 0);
                oacc[u][j] = __builtin_amdgcn_mfma_f32_16x16x32_bf16(pf1, vf[j][1], oacc[u][j], 0, 0, 0);
            }
        }
    }

    // final row-sum reduce (16 lanes share each row) and write
    #pragma unroll
    for (int u = 0; u < 2; ++u) {
        float inv[4];
        #pragma unroll
        for (int r = 0; r < 4; ++r) {
            float s = lrow[u][r];
            #pragma unroll
            for (int d = 1; d < 16; d <<= 1) s += __shfl_xor(s, d);
            inv[r] = 1.0f / s;
        }
        #pragma unroll
        for (int j = 0; j < 4; ++j) {
            int col = hcol + j * 16 + lm;
            #pragma unroll
            for (int r = 0; r < 4; ++r) {
                size_t row = qrow0 + u * 64 + wave * 16 + quad * 4 + r;
                o[row * 512 + col] = f2bf(oacc[u][j][r] * inv[r]);
            }
        }
    }
}

// ---------------------------------------------------------------------------
extern "C" void kernel_launch(void* const* d_in, const int* in_sizes, int n_in,
                              void* d_out, int out_size, void* d_ws, size_t ws_size,
                              hipStream_t stream)
{
    const float* x   = (const float*)d_in[0];
    const float* ctx = (const float*)d_in[1];
    const float* Wq  = (const float*)d_in[2];
    const float* Wk  = (const float*)d_in[3];
    const float* Wv  = (const float*)d_in[4];
    const float* Wo  = (const float*)d_in[5];
    const float* bo  = (const float*)d_in[6];

    char* ws = (char*)d_ws;
    short* xb   = (short*)(ws);                                    // 8 MB
    short* cb   = (short*)(ws + (8u << 20));                       // 6 MB
    short* wqT  = (short*)(ws + (14u << 20));                      // 0.5 MB
    short* wkvT = (short*)(ws + (14u << 20) + (512u << 10));       // 1.5 MB
    short* woT  = (short*)(ws + (16u << 20));                      // 0.5 MB
    short* qb   = (short*)(ws + (16u << 20) + (512u << 10));       // 8 MB
    short* kvb  = (short*)(ws + (24u << 20) + (512u << 10));       // 8 MB
    short* ob   = xb;   // xb dead after QKV GEMM
    short* vT   = cb;   // cb dead after QKV GEMM

    prep_kernel<<<8448, 256, 0, stream>>>(x, ctx, Wq, Wk, Wv, Wo,
                                          xb, cb, wqT, wkvT, woT);
    qkv_kernel<<<1024, 256, 0, stream>>>(xb, cb, wqT, wkvT, qb, kvb);
    vtrans_kernel<<<dim3(16, 32, 4), 256, 0, stream>>>(kvb + 512, vT);
    attn_kernel<<<dim3(16, 8, 4), 256, 0, stream>>>(qb, kvb, vT, ob);
    ogemm_kernel<<<512, 256, 0, stream>>>(ob, woT, bo, (float*)d_out);
}

// Round 5
// 199.501 us; speedup vs baseline: 1.0319x; 1.0319x over previous
//
#include <hip/hip_runtime.h>
#include <cstddef>
#include <cstdint>

typedef __attribute__((ext_vector_type(8))) short bf16x8;
typedef __attribute__((ext_vector_type(4))) float f32x4;

static __device__ __forceinline__ short f2bf(float f) {
    union { float f; unsigned u; } x;
    x.f = f;
    unsigned r = (x.u + 0x7FFFu + ((x.u >> 16) & 1u)) >> 16;  // RNE
    return (short)r;
}
static __device__ __forceinline__ short f2bf_fast(float f) {
    union { float f; unsigned u; } x;
    x.f = f;
    return (short)((x.u + 0x8000u) >> 16);
}

typedef __attribute__((address_space(3))) unsigned lds_u;
typedef const __attribute__((address_space(1))) unsigned glb_u;
static __device__ __forceinline__ void gld_lds16(const void* g, void* l) {
    __builtin_amdgcn_global_load_lds((glb_u*)g, (lds_u*)l, 16, 0, 0);
}

// ---------------------------------------------------------------------------
// prep: blocks [0,7168) convert x,ctx fp32->bf16; [7168,8448) transpose+convert
// weights to BT layout (Wk|Wv fused into wkvT [1024,768]).
// ---------------------------------------------------------------------------
__global__ __launch_bounds__(256) void prep_kernel(
    const float* __restrict__ x, const float* __restrict__ c,
    const float* __restrict__ Wq, const float* __restrict__ Wk,
    const float* __restrict__ Wv, const float* __restrict__ Wo,
    short* __restrict__ xb, short* __restrict__ cb,
    short* __restrict__ wqT, short* __restrict__ wkvT, short* __restrict__ woT)
{
    const int bid = blockIdx.x;
    const int tid = threadIdx.x;
    if (bid < 7168) {
        int i = bid * 256 + tid;                 // float4 index
        int nn1 = (8192 * 512) >> 2;
        const float* src; short* dst; int off;
        if (i < nn1) { src = x; dst = xb; off = i; }
        else { src = c; dst = cb; off = i - nn1; }
        float4 v = ((const float4*)src)[off];
        ushort4 w;
        w.x = (unsigned short)f2bf(v.x); w.y = (unsigned short)f2bf(v.y);
        w.z = (unsigned short)f2bf(v.z); w.w = (unsigned short)f2bf(v.w);
        ((ushort4*)dst)[off] = w;
        return;
    }
    __shared__ float T[32][33];
    int w = bid - 7168;
    const float* src; short* dst; int R, t;
    if (w < 256)       { src = Wq; dst = wqT;  R = 512; t = w; }
    else if (w < 640)  { src = Wk; dst = wkvT; R = 768; t = w - 256; }
    else if (w < 1024) { src = Wv; dst = wkvT + (size_t)512 * 768; R = 768; t = w - 640; }
    else               { src = Wo; dst = woT;  R = 512; t = w - 1024; }
    const int xt = t & 15, yt = t >> 4;
    {
        int r = tid >> 3, c4 = (tid & 7) * 4;
        float4 v = *(const float4*)&src[(size_t)(yt * 32 + r) * 512 + xt * 32 + c4];
        T[r][c4] = v.x; T[r][c4 + 1] = v.y; T[r][c4 + 2] = v.z; T[r][c4 + 3] = v.w;
    }
    __syncthreads();
    {
        int cc = tid >> 3, r4 = (tid & 7) * 4;
        ushort4 o;
        o.x = (unsigned short)f2bf(T[r4][cc]);     o.y = (unsigned short)f2bf(T[r4 + 1][cc]);
        o.z = (unsigned short)f2bf(T[r4 + 2][cc]); o.w = (unsigned short)f2bf(T[r4 + 3][cc]);
        *(ushort4*)&dst[(size_t)(xt * 32 + cc) * R + yt * 32 + r4] = o;
    }
}

// ---------------------------------------------------------------------------
// V transpose (bf16): kvb v-half [4][1024][512] (ld 1024) -> vT [4][512][1024]
// ---------------------------------------------------------------------------
__global__ __launch_bounds__(256) void vtrans_kernel(
    const short* __restrict__ v, short* __restrict__ vT)
{
    __shared__ short T[32][33];
    const int b = blockIdx.z, yt = blockIdx.y, xt = blockIdx.x;
    const int tid = threadIdx.x;
    {
        int r = tid >> 3, c4 = (tid & 7) * 4;
        ushort4 vv = *(const ushort4*)&v[((size_t)(b * 1024 + yt * 32 + r)) * 1024 + xt * 32 + c4];
        T[r][c4] = (short)vv.x; T[r][c4 + 1] = (short)vv.y;
        T[r][c4 + 2] = (short)vv.z; T[r][c4 + 3] = (short)vv.w;
    }
    __syncthreads();
    {
        int cc = tid >> 3, r4 = (tid & 7) * 4;
        ushort4 w;
        w.x = (unsigned short)T[r4][cc];     w.y = (unsigned short)T[r4 + 1][cc];
        w.z = (unsigned short)T[r4 + 2][cc]; w.w = (unsigned short)T[r4 + 3][cc];
        *(ushort4*)&vT[((size_t)(b * 512 + xt * 32 + cc)) * 1024 + yt * 32 + r4] = w;
    }
}

// ---------------------------------------------------------------------------
// Barrier-free register-streaming GEMM core. Block = 4 waves stacked on M
// (tile 256 x 64); wave = 64x64 (4x4 MFMA). NO LDS, NO __syncthreads.
// A/B fragments are 16B-contiguous per lane in BT layout -> direct
// global_load_dwordx4 (one 64B line per row per iter, perfectly sectored).
// B (weights) is L2-resident + L1-shared across the 4 waves. The compiler
// software-pipelines these regular loads with fine-grained vmcnt(N) -- the
// thing the DMA+syncthreads structure could not do (vmcnt(0) barrier drain).
// ---------------------------------------------------------------------------
static __device__ __forceinline__ void gemm_reg_core(
    const short* __restrict__ A, const short* __restrict__ BT, int K,
    int bm, int bn, f32x4 acc[4][4])
{
    const int lane = threadIdx.x & 63;
    const int wave = threadIdx.x >> 6;
    const int lm = lane & 15, quad = lane >> 4;

    const short* Ab = A  + (size_t)(bm + wave * 64 + lm) * K + quad * 8;
    const short* Bb = BT + (size_t)(bn + lm) * K + quad * 8;
    const size_t rsA = (size_t)16 * K;   // 16-row step
    const size_t rsB = (size_t)16 * K;

    bf16x8 af[4], bfr[4], afn[4], bfn[4];
    #pragma unroll
    for (int i = 0; i < 4; ++i) af[i]  = *(const bf16x8*)(Ab + i * rsA);
    #pragma unroll
    for (int j = 0; j < 4; ++j) bfr[j] = *(const bf16x8*)(Bb + j * rsB);

    const int nit = K >> 5;
    for (int it = 0; it < nit; ++it) {
        if (it + 1 < nit) {
            const short* An = Ab + (it + 1) * 32;
            const short* Bn = Bb + (it + 1) * 32;
            #pragma unroll
            for (int i = 0; i < 4; ++i) afn[i] = *(const bf16x8*)(An + i * rsA);
            #pragma unroll
            for (int j = 0; j < 4; ++j) bfn[j] = *(const bf16x8*)(Bn + j * rsB);
        }
        #pragma unroll
        for (int i = 0; i < 4; ++i)
            #pragma unroll
            for (int j = 0; j < 4; ++j)
                acc[i][j] = __builtin_amdgcn_mfma_f32_16x16x32_bf16(
                    af[i], bfr[j], acc[i][j], 0, 0, 0);
        #pragma unroll
        for (int i = 0; i < 4; ++i) { af[i] = afn[i]; bfr[i] = bfn[i]; }
    }
}

// Fused Q + KV projection. blocks [0,256): q = xb@wqT (tiles 32x8);
// [256,512): kv = cb@wkvT (tiles 16x16). Output bf16.
__global__ __launch_bounds__(256) void qkv_kernel(
    const short* __restrict__ xb, const short* __restrict__ cb,
    const short* __restrict__ wqT, const short* __restrict__ wkvT,
    short* __restrict__ qb, short* __restrict__ kvb)
{
    const int bid = blockIdx.x;
    const short *A, *BT; short* C; int K, ldc, bm, bn;
    if (bid < 256) { A = xb; BT = wqT;  C = qb;  K = 512; ldc = 512;
                     bm = (bid >> 3) * 256; bn = (bid & 7) * 64; }
    else { int b2 = bid - 256; A = cb; BT = wkvT; C = kvb; K = 768; ldc = 1024;
           bm = (b2 >> 4) * 256; bn = (b2 & 15) * 64; }

    f32x4 acc[4][4] = {};
    gemm_reg_core(A, BT, K, bm, bn, acc);

    const int lane = threadIdx.x & 63, wave = threadIdx.x >> 6;
    const int lm = lane & 15, quad = lane >> 4;
    #pragma unroll
    for (int j = 0; j < 4; ++j) {
        int col = bn + j * 16 + lm;
        #pragma unroll
        for (int i = 0; i < 4; ++i) {
            int row0 = bm + wave * 64 + i * 16 + quad * 4;
            #pragma unroll
            for (int r = 0; r < 4; ++r)
                C[(size_t)(row0 + r) * ldc + col] = f2bf(acc[i][j][r]);
        }
    }
}

// Output projection: out = ob@woT + bo (fp32). Grid 256 (tiles 32x8).
__global__ __launch_bounds__(256) void ogemm_kernel(
    const short* __restrict__ ob, const short* __restrict__ woT,
    const float* __restrict__ bias, float* __restrict__ out)
{
    const int bid = blockIdx.x;
    const int bm = (bid >> 3) * 256, bn = (bid & 7) * 64;

    f32x4 acc[4][4] = {};
    gemm_reg_core(ob, woT, 512, bm, bn, acc);

    const int lane = threadIdx.x & 63, wave = threadIdx.x >> 6;
    const int lm = lane & 15, quad = lane >> 4;
    #pragma unroll
    for (int j = 0; j < 4; ++j) {
        int col = bn + j * 16 + lm;
        float bv = bias[col];
        #pragma unroll
        for (int i = 0; i < 4; ++i) {
            int row0 = bm + wave * 64 + i * 16 + quad * 4;
            #pragma unroll
            for (int r = 0; r < 4; ++r)
                out[(size_t)(row0 + r) * 512 + col] = acc[i][j][r] + bv;
        }
    }
}

// ---------------------------------------------------------------------------
// Flash attention (round-3 proven version, 52.8 us). Block = (b,h,64 q-rows),
// 4 waves. Fixed-max softmax: exp2(s*C1 - C2) -- exact by shift invariance,
// s ~ N(0,1) so no overflow. K/V dbuf (one barrier/tile). P round-trips the
// dead Q-staging LDS per wave with XOR-swizzled chunks (b128 reads 2-way=free).
// ---------------------------------------------------------------------------
__global__ __launch_bounds__(256) void attn_kernel(
    const short* __restrict__ q, const short* __restrict__ k,
    const short* __restrict__ vT, short* __restrict__ o)
{
    __shared__ short Qs[4096];          // Q staging, then per-wave P buffers
    __shared__ short Ks[2 * 4096];
    __shared__ short Vs[2 * 4096];

    const int tid  = threadIdx.x;
    const int lane = tid & 63;
    const int wave = tid >> 6;
    const int lm   = lane & 15;
    const int quad = lane >> 4;
    const int qt = blockIdx.x, h = blockIdx.y, b = blockIdx.z;
    const size_t qrow0 = (size_t)b * 2048 + qt * 64;
    const size_t krow0 = (size_t)b * 1024;
    const int hcol = h * 64;
    const size_t vrow0 = ((size_t)b * 8 + h) * 64;

    #pragma unroll
    for (int p = 0; p < 2; ++p) {
        int idx = p * 256 + tid;
        int c = idx >> 6, r = idx & 63;
        gld_lds16(&q[(qrow0 + r) * 512 + hcol + c * 8], &Qs[idx * 8]);
        gld_lds16(&k[(krow0 + r) * 1024 + hcol + c * 8], &Ks[idx * 8]);
        gld_lds16(&vT[(vrow0 + r) * 1024 + c * 8], &Vs[idx * 8]);
    }
    __syncthreads();
    bf16x8 qf0 = *(const bf16x8*)&Qs[((0 + quad) * 64 + wave * 16 + lm) * 8];
    bf16x8 qf1 = *(const bf16x8*)&Qs[((4 + quad) * 64 + wave * 16 + lm) * 8];
    // Qs reused as P buffer below; first P write happens after the t-loop's
    // first __syncthreads, which orders it after all waves' qf reads.

    short* Pw = &Qs[wave * 1024];
    const int pr0 = lm * 64 + ((quad ^ (lm & 7)) << 3);
    const int pr1 = lm * 64 + (((quad + 4) ^ (lm & 7)) << 3);

    constexpr float C1 = 0.18033688f;   // 0.125 * log2(e)
    constexpr float C2 = 11.5415603f;   // 8 * log2(e)

    f32x4 oacc[4] = {};
    float lrow[4] = {0.0f, 0.0f, 0.0f, 0.0f};

    for (int t = 0; t < 16; ++t) {
        const short* Kc = &Ks[(t & 1) * 4096];
        const short* Vc = &Vs[(t & 1) * 4096];
        __syncthreads();
        if (t + 1 < 16) {
            short* Kn = &Ks[((t + 1) & 1) * 4096];
            short* Vn = &Vs[((t + 1) & 1) * 4096];
            #pragma unroll
            for (int p = 0; p < 2; ++p) {
                int idx = p * 256 + tid;
                int c = idx >> 6, r = idx & 63;
                gld_lds16(&k[(krow0 + (t + 1) * 64 + r) * 1024 + hcol + c * 8], &Kn[idx * 8]);
                gld_lds16(&vT[(vrow0 + r) * 1024 + (t + 1) * 64 + c * 8], &Vn[idx * 8]);
            }
        }

        f32x4 sacc[4] = {};
        #pragma unroll
        for (int j = 0; j < 4; ++j) {
            bf16x8 kf0 = *(const bf16x8*)&Kc[((0 + quad) * 64 + j * 16 + lm) * 8];
            bf16x8 kf1 = *(const bf16x8*)&Kc[((4 + quad) * 64 + j * 16 + lm) * 8];
            sacc[j] = __builtin_amdgcn_mfma_f32_16x16x32_bf16(qf0, kf0, sacc[j], 0, 0, 0);
            sacc[j] = __builtin_amdgcn_mfma_f32_16x16x32_bf16(qf1, kf1, sacc[j], 0, 0, 0);
        }

        #pragma unroll
        for (int r = 0; r < 4; ++r) {
            int row = quad * 4 + r;
            int rsw = (row & 7);
            float lsum = 0.0f;
            #pragma unroll
            for (int j = 0; j < 4; ++j) {
                float pv = exp2f(fmaf(sacc[j][r], C1, -C2));
                lsum += pv;
                int cc = (2 * j + (lm >> 3)) ^ rsw;
                Pw[row * 64 + (cc << 3) + (lm & 7)] = f2bf_fast(pv);
            }
            lrow[r] += lsum;
        }
        bf16x8 pf0 = *(const bf16x8*)&Pw[pr0];
        bf16x8 pf1 = *(const bf16x8*)&Pw[pr1];

        #pragma unroll
        for (int j = 0; j < 4; ++j) {
            bf16x8 vf0 = *(const bf16x8*)&Vc[((0 + quad) * 64 + j * 16 + lm) * 8];
            bf16x8 vf1 = *(const bf16x8*)&Vc[((4 + quad) * 64 + j * 16 + lm) * 8];
            oacc[j] = __builtin_amdgcn_mfma_f32_16x16x32_bf16(pf0, vf0, oacc[j], 0, 0, 0);
            oacc[j] = __builtin_amdgcn_mfma_f32_16x16x32_bf16(pf1, vf1, oacc[j], 0, 0, 0);
        }
    }

    float inv[4];
    #pragma unroll
    for (int r = 0; r < 4; ++r) {
        float s = lrow[r];
        #pragma unroll
        for (int d = 1; d < 16; d <<= 1) s += __shfl_xor(s, d);
        inv[r] = 1.0f / s;
    }
    #pragma unroll
    for (int j = 0; j < 4; ++j) {
        int col = hcol + j * 16 + lm;
        #pragma unroll
        for (int r = 0; r < 4; ++r) {
            size_t row = qrow0 + wave * 16 + quad * 4 + r;
            o[row * 512 + col] = f2bf(oacc[j][r] * inv[r]);
        }
    }
}

// ---------------------------------------------------------------------------
extern "C" void kernel_launch(void* const* d_in, const int* in_sizes, int n_in,
                              void* d_out, int out_size, void* d_ws, size_t ws_size,
                              hipStream_t stream)
{
    const float* x   = (const float*)d_in[0];
    const float* ctx = (const float*)d_in[1];
    const float* Wq  = (const float*)d_in[2];
    const float* Wk  = (const float*)d_in[3];
    const float* Wv  = (const float*)d_in[4];
    const float* Wo  = (const float*)d_in[5];
    const float* bo  = (const float*)d_in[6];

    char* ws = (char*)d_ws;
    short* xb   = (short*)(ws);                                    // 8 MB
    short* cb   = (short*)(ws + (8u << 20));                       // 6 MB
    short* wqT  = (short*)(ws + (14u << 20));                      // 0.5 MB
    short* wkvT = (short*)(ws + (14u << 20) + (512u << 10));       // 1.5 MB
    short* woT  = (short*)(ws + (16u << 20));                      // 0.5 MB
    short* qb   = (short*)(ws + (16u << 20) + (512u << 10));       // 8 MB
    short* kvb  = (short*)(ws + (24u << 20) + (512u << 10));       // 8 MB
    short* ob   = xb;   // xb dead after QKV GEMM
    short* vT   = cb;   // cb dead after QKV GEMM

    prep_kernel<<<8448, 256, 0, stream>>>(x, ctx, Wq, Wk, Wv, Wo,
                                          xb, cb, wqT, wkvT, woT);
    qkv_kernel<<<512, 256, 0, stream>>>(xb, cb, wqT, wkvT, qb, kvb);
    vtrans_kernel<<<dim3(16, 32, 4), 256, 0, stream>>>(kvb + 512, vT);
    attn_kernel<<<dim3(32, 8, 4), 256, 0, stream>>>(qb, kvb, vT, ob);
    ogemm_kernel<<<256, 256, 0, stream>>>(ob, woT, bo, (float*)d_out);
}

// Round 6
// 192.420 us; speedup vs baseline: 1.0699x; 1.0368x over previous
//
#include <hip/hip_runtime.h>
#include <cstddef>
#include <cstdint>

typedef __attribute__((ext_vector_type(8))) short bf16x8;
typedef __attribute__((ext_vector_type(4))) float f32x4;

static __device__ __forceinline__ short f2bf(float f) {
    union { float f; unsigned u; } x;
    x.f = f;
    unsigned r = (x.u + 0x7FFFu + ((x.u >> 16) & 1u)) >> 16;  // RNE
    return (short)r;
}
static __device__ __forceinline__ short f2bf_fast(float f) {
    union { float f; unsigned u; } x;
    x.f = f;
    return (short)((x.u + 0x8000u) >> 16);
}

typedef __attribute__((address_space(3))) unsigned lds_u;
typedef const __attribute__((address_space(1))) unsigned glb_u;
static __device__ __forceinline__ void gld_lds16(const void* g, void* l) {
    __builtin_amdgcn_global_load_lds((glb_u*)g, (lds_u*)l, 16, 0, 0);
}

// ---------------------------------------------------------------------------
// prep: blocks [0,7168) convert x,ctx fp32->bf16; [7168,8448) transpose+convert
// weights to BT layout (Wk|Wv fused into wkvT [1024,768]).
// ---------------------------------------------------------------------------
__global__ __launch_bounds__(256) void prep_kernel(
    const float* __restrict__ x, const float* __restrict__ c,
    const float* __restrict__ Wq, const float* __restrict__ Wk,
    const float* __restrict__ Wv, const float* __restrict__ Wo,
    short* __restrict__ xb, short* __restrict__ cb,
    short* __restrict__ wqT, short* __restrict__ wkvT, short* __restrict__ woT)
{
    const int bid = blockIdx.x;
    const int tid = threadIdx.x;
    if (bid < 7168) {
        int i = bid * 256 + tid;                 // float4 index
        int nn1 = (8192 * 512) >> 2;
        const float* src; short* dst; int off;
        if (i < nn1) { src = x; dst = xb; off = i; }
        else { src = c; dst = cb; off = i - nn1; }
        float4 v = ((const float4*)src)[off];
        ushort4 w;
        w.x = (unsigned short)f2bf(v.x); w.y = (unsigned short)f2bf(v.y);
        w.z = (unsigned short)f2bf(v.z); w.w = (unsigned short)f2bf(v.w);
        ((ushort4*)dst)[off] = w;
        return;
    }
    __shared__ float T[32][33];
    int w = bid - 7168;
    const float* src; short* dst; int R, t;
    if (w < 256)       { src = Wq; dst = wqT;  R = 512; t = w; }
    else if (w < 640)  { src = Wk; dst = wkvT; R = 768; t = w - 256; }
    else if (w < 1024) { src = Wv; dst = wkvT + (size_t)512 * 768; R = 768; t = w - 640; }
    else               { src = Wo; dst = woT;  R = 512; t = w - 1024; }
    const int xt = t & 15, yt = t >> 4;
    {
        int r = tid >> 3, c4 = (tid & 7) * 4;
        float4 v = *(const float4*)&src[(size_t)(yt * 32 + r) * 512 + xt * 32 + c4];
        T[r][c4] = v.x; T[r][c4 + 1] = v.y; T[r][c4 + 2] = v.z; T[r][c4 + 3] = v.w;
    }
    __syncthreads();
    {
        int cc = tid >> 3, r4 = (tid & 7) * 4;
        ushort4 o;
        o.x = (unsigned short)f2bf(T[r4][cc]);     o.y = (unsigned short)f2bf(T[r4 + 1][cc]);
        o.z = (unsigned short)f2bf(T[r4 + 2][cc]); o.w = (unsigned short)f2bf(T[r4 + 3][cc]);
        *(ushort4*)&dst[(size_t)(xt * 32 + cc) * R + yt * 32 + r4] = o;
    }
}

// ---------------------------------------------------------------------------
// V transpose (bf16): kvb v-half [4][1024][512] (ld 1024) -> vT [4][512][1024]
// ---------------------------------------------------------------------------
__global__ __launch_bounds__(256) void vtrans_kernel(
    const short* __restrict__ v, short* __restrict__ vT)
{
    __shared__ short T[32][33];
    const int b = blockIdx.z, yt = blockIdx.y, xt = blockIdx.x;
    const int tid = threadIdx.x;
    {
        int r = tid >> 3, c4 = (tid & 7) * 4;
        ushort4 vv = *(const ushort4*)&v[((size_t)(b * 1024 + yt * 32 + r)) * 1024 + xt * 32 + c4];
        T[r][c4] = (short)vv.x; T[r][c4 + 1] = (short)vv.y;
        T[r][c4 + 2] = (short)vv.z; T[r][c4 + 3] = (short)vv.w;
    }
    __syncthreads();
    {
        int cc = tid >> 3, r4 = (tid & 7) * 4;
        ushort4 w;
        w.x = (unsigned short)T[r4][cc];     w.y = (unsigned short)T[r4 + 1][cc];
        w.z = (unsigned short)T[r4 + 2][cc]; w.w = (unsigned short)T[r4 + 3][cc];
        *(ushort4*)&vT[((size_t)(b * 512 + xt * 32 + cc)) * 1024 + yt * 32 + r4] = w;
    }
}

// ---------------------------------------------------------------------------
// Hybrid GEMM core: C[128,128] tile, 4 waves (2x2, wave 64x64, 4x4 MFMA).
// A: global->LDS DMA in BK=64 windows (4 DMA/thread in flight -> 2x drain
//    rate vs BK=32; dbuf 32 KB; one barrier per window, 8-12 windows total).
// B: weights (L2-resident) streamed per-lane into registers (16B contiguous
//    frags), prefetched half-a-window ahead -- not subject to barrier drain.
// ---------------------------------------------------------------------------
static __device__ __forceinline__ void gemm_hyb(
    const short* __restrict__ A, const short* __restrict__ BT, int K,
    int bm, int bn, short* As, f32x4 acc[4][4])
{
    const int tid = threadIdx.x, lane = tid & 63, wave = tid >> 6;
    const int lm = lane & 15, quad = lane >> 4;
    const int wm = (wave >> 1) * 64, wn = (wave & 1) * 64;
    const int cs = tid >> 7, rs = tid & 127;     // staging coords

    const short* Ag = A + (size_t)(bm + rs) * K;
    const short* Bb = BT + (size_t)(bn + wn + lm) * K + quad * 8;
    const size_t rsB = (size_t)16 * K;

    // prologue: DMA window 0 (A k[0,64)), load B(w0, half0)
    #pragma unroll
    for (int p = 0; p < 4; ++p)
        gld_lds16(Ag + (cs + 2 * p) * 8, As + ((cs + 2 * p) * 128 + rs) * 8);
    bf16x8 b0[4], b1[4], b2[4];
    #pragma unroll
    for (int j = 0; j < 4; ++j) b0[j] = *(const bf16x8*)(Bb + j * rsB);

    const int nw = K >> 6;
    for (int w = 0; w < nw; ++w) {
        short* Ac = As + (w & 1) * 8192;
        __syncthreads();                          // drains DMA(w), issued 1 window ago
        if (w + 1 < nw) {                         // DMA window w+1
            short* An = As + ((w + 1) & 1) * 8192;
            const short* Agn = Ag + (w + 1) * 64;
            #pragma unroll
            for (int p = 0; p < 4; ++p)
                gld_lds16(Agn + (cs + 2 * p) * 8, An + ((cs + 2 * p) * 128 + rs) * 8);
        }
        #pragma unroll
        for (int j = 0; j < 4; ++j)               // B(w, half1) - hides under half0 MFMAs
            b1[j] = *(const bf16x8*)(Bb + w * 64 + 32 + j * rsB);
        #pragma unroll
        for (int i = 0; i < 4; ++i) {             // half 0
            bf16x8 af = *(const bf16x8*)&Ac[(quad * 128 + wm + i * 16 + lm) * 8];
            #pragma unroll
            for (int j = 0; j < 4; ++j)
                acc[i][j] = __builtin_amdgcn_mfma_f32_16x16x32_bf16(af, b0[j], acc[i][j], 0, 0, 0);
        }
        if (w + 1 < nw) {
            #pragma unroll
            for (int j = 0; j < 4; ++j)           // B(w+1, half0) - hides under half1 MFMAs
                b2[j] = *(const bf16x8*)(Bb + (w + 1) * 64 + j * rsB);
        }
        #pragma unroll
        for (int i = 0; i < 4; ++i) {             // half 1
            bf16x8 af = *(const bf16x8*)&Ac[((4 + quad) * 128 + wm + i * 16 + lm) * 8];
            #pragma unroll
            for (int j = 0; j < 4; ++j)
                acc[i][j] = __builtin_amdgcn_mfma_f32_16x16x32_bf16(af, b1[j], acc[i][j], 0, 0, 0);
        }
        #pragma unroll
        for (int j = 0; j < 4; ++j) b0[j] = b2[j];
    }
}

// Fused Q + KV projection. blocks [0,256): q = xb@wqT; [256,512): kv = cb@wkvT.
__global__ __launch_bounds__(256) void qkv_kernel(
    const short* __restrict__ xb, const short* __restrict__ cb,
    const short* __restrict__ wqT, const short* __restrict__ wkvT,
    short* __restrict__ qb, short* __restrict__ kvb)
{
    __shared__ short As[2 * 8192];
    const int bid = blockIdx.x;
    const short *A, *BT; short* C; int K, ldc, bm, bn;
    if (bid < 256) { A = xb; BT = wqT;  C = qb;  K = 512; ldc = 512;
                     bm = (bid >> 2) * 128; bn = (bid & 3) * 128; }
    else { int b2 = bid - 256; A = cb; BT = wkvT; C = kvb; K = 768; ldc = 1024;
           bm = (b2 >> 3) * 128; bn = (b2 & 7) * 128; }

    f32x4 acc[4][4] = {};
    gemm_hyb(A, BT, K, bm, bn, As, acc);

    const int lane = threadIdx.x & 63, wave = threadIdx.x >> 6;
    const int lm = lane & 15, quad = lane >> 4;
    const int wm = (wave >> 1) * 64, wn = (wave & 1) * 64;
    #pragma unroll
    for (int j = 0; j < 4; ++j) {
        int col = bn + wn + j * 16 + lm;
        #pragma unroll
        for (int i = 0; i < 4; ++i) {
            int row0 = bm + wm + i * 16 + quad * 4;
            #pragma unroll
            for (int r = 0; r < 4; ++r)
                C[(size_t)(row0 + r) * ldc + col] = f2bf(acc[i][j][r]);
        }
    }
}

// Output projection: out = ob@woT + bo (fp32). Grid 256.
__global__ __launch_bounds__(256) void ogemm_kernel(
    const short* __restrict__ ob, const short* __restrict__ woT,
    const float* __restrict__ bias, float* __restrict__ out)
{
    __shared__ short As[2 * 8192];
    const int bid = blockIdx.x;
    const int bm = (bid >> 2) * 128, bn = (bid & 3) * 128;

    f32x4 acc[4][4] = {};
    gemm_hyb(ob, woT, 512, bm, bn, As, acc);

    const int lane = threadIdx.x & 63, wave = threadIdx.x >> 6;
    const int lm = lane & 15, quad = lane >> 4;
    const int wm = (wave >> 1) * 64, wn = (wave & 1) * 64;
    #pragma unroll
    for (int j = 0; j < 4; ++j) {
        int col = bn + wn + j * 16 + lm;
        float bv = bias[col];
        #pragma unroll
        for (int i = 0; i < 4; ++i) {
            int row0 = bm + wm + i * 16 + quad * 4;
            #pragma unroll
            for (int r = 0; r < 4; ++r)
                out[(size_t)(row0 + r) * 512 + col] = acc[i][j][r] + bv;
        }
    }
}

// ---------------------------------------------------------------------------
// Flash attention (round-5 proven, 49.1 us). Block = (b,h,64 q-rows), 4 waves.
// Fixed-max softmax exp2(s*C1 - C2); K/V dbuf; P via swizzled LDS round-trip.
// ---------------------------------------------------------------------------
__global__ __launch_bounds__(256) void attn_kernel(
    const short* __restrict__ q, const short* __restrict__ k,
    const short* __restrict__ vT, short* __restrict__ o)
{
    __shared__ short Qs[4096];          // Q staging, then per-wave P buffers
    __shared__ short Ks[2 * 4096];
    __shared__ short Vs[2 * 4096];

    const int tid  = threadIdx.x;
    const int lane = tid & 63;
    const int wave = tid >> 6;
    const int lm   = lane & 15;
    const int quad = lane >> 4;
    const int qt = blockIdx.x, h = blockIdx.y, b = blockIdx.z;
    const size_t qrow0 = (size_t)b * 2048 + qt * 64;
    const size_t krow0 = (size_t)b * 1024;
    const int hcol = h * 64;
    const size_t vrow0 = ((size_t)b * 8 + h) * 64;

    #pragma unroll
    for (int p = 0; p < 2; ++p) {
        int idx = p * 256 + tid;
        int c = idx >> 6, r = idx & 63;
        gld_lds16(&q[(qrow0 + r) * 512 + hcol + c * 8], &Qs[idx * 8]);
        gld_lds16(&k[(krow0 + r) * 1024 + hcol + c * 8], &Ks[idx * 8]);
        gld_lds16(&vT[(vrow0 + r) * 1024 + c * 8], &Vs[idx * 8]);
    }
    __syncthreads();
    bf16x8 qf0 = *(const bf16x8*)&Qs[((0 + quad) * 64 + wave * 16 + lm) * 8];
    bf16x8 qf1 = *(const bf16x8*)&Qs[((4 + quad) * 64 + wave * 16 + lm) * 8];

    short* Pw = &Qs[wave * 1024];
    const int pr0 = lm * 64 + ((quad ^ (lm & 7)) << 3);
    const int pr1 = lm * 64 + (((quad + 4) ^ (lm & 7)) << 3);

    constexpr float C1 = 0.18033688f;   // 0.125 * log2(e)
    constexpr float C2 = 11.5415603f;   // 8 * log2(e)

    f32x4 oacc[4] = {};
    float lrow[4] = {0.0f, 0.0f, 0.0f, 0.0f};

    for (int t = 0; t < 16; ++t) {
        const short* Kc = &Ks[(t & 1) * 4096];
        const short* Vc = &Vs[(t & 1) * 4096];
        __syncthreads();
        if (t + 1 < 16) {
            short* Kn = &Ks[((t + 1) & 1) * 4096];
            short* Vn = &Vs[((t + 1) & 1) * 4096];
            #pragma unroll
            for (int p = 0; p < 2; ++p) {
                int idx = p * 256 + tid;
                int c = idx >> 6, r = idx & 63;
                gld_lds16(&k[(krow0 + (t + 1) * 64 + r) * 1024 + hcol + c * 8], &Kn[idx * 8]);
                gld_lds16(&vT[(vrow0 + r) * 1024 + (t + 1) * 64 + c * 8], &Vn[idx * 8]);
            }
        }

        f32x4 sacc[4] = {};
        #pragma unroll
        for (int j = 0; j < 4; ++j) {
            bf16x8 kf0 = *(const bf16x8*)&Kc[((0 + quad) * 64 + j * 16 + lm) * 8];
            bf16x8 kf1 = *(const bf16x8*)&Kc[((4 + quad) * 64 + j * 16 + lm) * 8];
            sacc[j] = __builtin_amdgcn_mfma_f32_16x16x32_bf16(qf0, kf0, sacc[j], 0, 0, 0);
            sacc[j] = __builtin_amdgcn_mfma_f32_16x16x32_bf16(qf1, kf1, sacc[j], 0, 0, 0);
        }

        #pragma unroll
        for (int r = 0; r < 4; ++r) {
            int row = quad * 4 + r;
            int rsw = (row & 7);
            float lsum = 0.0f;
            #pragma unroll
            for (int j = 0; j < 4; ++j) {
                float pv = exp2f(fmaf(sacc[j][r], C1, -C2));
                lsum += pv;
                int cc = (2 * j + (lm >> 3)) ^ rsw;
                Pw[row * 64 + (cc << 3) + (lm & 7)] = f2bf_fast(pv);
            }
            lrow[r] += lsum;
        }
        bf16x8 pf0 = *(const bf16x8*)&Pw[pr0];
        bf16x8 pf1 = *(const bf16x8*)&Pw[pr1];

        #pragma unroll
        for (int j = 0; j < 4; ++j) {
            bf16x8 vf0 = *(const bf16x8*)&Vc[((0 + quad) * 64 + j * 16 + lm) * 8];
            bf16x8 vf1 = *(const bf16x8*)&Vc[((4 + quad) * 64 + j * 16 + lm) * 8];
            oacc[j] = __builtin_amdgcn_mfma_f32_16x16x32_bf16(pf0, vf0, oacc[j], 0, 0, 0);
            oacc[j] = __builtin_amdgcn_mfma_f32_16x16x32_bf16(pf1, vf1, oacc[j], 0, 0, 0);
        }
    }

    float inv[4];
    #pragma unroll
    for (int r = 0; r < 4; ++r) {
        float s = lrow[r];
        #pragma unroll
        for (int d = 1; d < 16; d <<= 1) s += __shfl_xor(s, d);
        inv[r] = 1.0f / s;
    }
    #pragma unroll
    for (int j = 0; j < 4; ++j) {
        int col = hcol + j * 16 + lm;
        #pragma unroll
        for (int r = 0; r < 4; ++r) {
            size_t row = qrow0 + wave * 16 + quad * 4 + r;
            o[row * 512 + col] = f2bf(oacc[j][r] * inv[r]);
        }
    }
}

// ---------------------------------------------------------------------------
extern "C" void kernel_launch(void* const* d_in, const int* in_sizes, int n_in,
                              void* d_out, int out_size, void* d_ws, size_t ws_size,
                              hipStream_t stream)
{
    const float* x   = (const float*)d_in[0];
    const float* ctx = (const float*)d_in[1];
    const float* Wq  = (const float*)d_in[2];
    const float* Wk  = (const float*)d_in[3];
    const float* Wv  = (const float*)d_in[4];
    const float* Wo  = (const float*)d_in[5];
    const float* bo  = (const float*)d_in[6];

    char* ws = (char*)d_ws;
    short* xb   = (short*)(ws);                                    // 8 MB
    short* cb   = (short*)(ws + (8u << 20));                       // 6 MB
    short* wqT  = (short*)(ws + (14u << 20));                      // 0.5 MB
    short* wkvT = (short*)(ws + (14u << 20) + (512u << 10));       // 1.5 MB
    short* woT  = (short*)(ws + (16u << 20));                      // 0.5 MB
    short* qb   = (short*)(ws + (16u << 20) + (512u << 10));       // 8 MB
    short* kvb  = (short*)(ws + (24u << 20) + (512u << 10));       // 8 MB
    short* ob   = xb;   // xb dead after QKV GEMM
    short* vT   = cb;   // cb dead after QKV GEMM

    prep_kernel<<<8448, 256, 0, stream>>>(x, ctx, Wq, Wk, Wv, Wo,
                                          xb, cb, wqT, wkvT, woT);
    qkv_kernel<<<512, 256, 0, stream>>>(xb, cb, wqT, wkvT, qb, kvb);
    vtrans_kernel<<<dim3(16, 32, 4), 256, 0, stream>>>(kvb + 512, vT);
    attn_kernel<<<dim3(32, 8, 4), 256, 0, stream>>>(qb, kvb, vT, ob);
    ogemm_kernel<<<256, 256, 0, stream>>>(ob, woT, bo, (float*)d_out);
}